// Round 16
// baseline (180.582 us; speedup 1.0000x reference)
//
#include <hip/hip_runtime.h>
#include <hip/hip_bf16.h>

typedef __bf16 bf16_t;
typedef __attribute__((ext_vector_type(8))) __bf16 bf16x8;
typedef __attribute__((ext_vector_type(4))) __bf16 bf16x4;
typedef __attribute__((ext_vector_type(4))) float f32x4;
typedef __attribute__((ext_vector_type(16))) float f32x16;

#define MFMA16(A,B,C) __builtin_amdgcn_mfma_f32_16x16x32_bf16((A),(B),(C),0,0,0)
#define MFMA32(A,B,C) __builtin_amdgcn_mfma_f32_32x32x16_bf16((A),(B),(C),0,0,0)

#define BATCH 2
#define SEQ 2048
#define DMODEL 1024
#define NHEAD 16
#define HDIM 64
#define MROWS (BATCH * SEQ)   // 4096

// async 16B global->LDS. Global addr may be per-lane; LDS dest is
// wave-uniform base + lane*16.
__device__ __forceinline__ void async16(const bf16_t* g, bf16_t* l) {
    __builtin_amdgcn_global_load_lds(
        (const __attribute__((address_space(1))) unsigned int*)g,
        (__attribute__((address_space(3))) unsigned int*)l, 16, 0, 0);
}

// swizzled fragment loads: physical chunk = logical chunk ^ f(row)
// rows of 32 elems (64B, 4 chunks): f(row) = (row>>1)&3
__device__ __forceinline__ bf16x8 ldsA32(const bf16_t* base, int row, int chunk) {
    return *(const bf16x8*)&base[row * 32 + ((chunk ^ ((row >> 1) & 3)) << 3)];
}

// pack two fp32 -> 2 bf16 in one u32 (RNE)
__device__ __forceinline__ unsigned pk(float a, float b) {
    union { unsigned u; bf16_t h[2]; } t;
    t.h[0] = (bf16_t)a;
    t.h[1] = (bf16_t)b;
    return t.u;
}

// ---------------------------------------------------------------------------
// Fused splits. Blocks 0..4095: x -> bf16. Blocks 4096..8191: weights (hi
// only) with head-reorder (z<3: row r'=h*64+d takes old 16*d+h; Wq scaled
// 0.125*log2e so attention can use exp2); z==3 (Wo): identity order.
// ---------------------------------------------------------------------------
__global__ void split_kernel(const float* __restrict__ x, const float* __restrict__ Wq,
                             const float* __restrict__ Wk, const float* __restrict__ Wv,
                             const float* __restrict__ Wo, bf16_t* __restrict__ xh,
                             bf16_t* __restrict__ wh) {
    int blk = blockIdx.x;
    if (blk < 4096) {
        int i = blk * 256 + threadIdx.x;
        f32x4 v = ((const f32x4*)x)[i];
        bf16x4 h;
#pragma unroll
        for (int c = 0; c < 4; ++c) h[c] = (bf16_t)v[c];
        ((bf16x4*)xh)[i] = h;
        return;
    }
    int e = blk - 4096;
    int z = e >> 10;
    int i = (e & 1023) * 256 + threadIdx.x;       // 0..262143 (WE/4)
    const float* src = (z == 0) ? Wq : (z == 1) ? Wk : (z == 2) ? Wv : Wo;
    const float scale = (z == 0) ? 0.125f * 1.44269504088896f : 1.0f;
    int row = i >> 8, col4 = i & 255;
    int r_src;
    if (z < 3) {
        int h = row >> 6, d = row & 63;
        r_src = 16 * d + h;
    } else {
        r_src = row;
    }
    f32x4 v = ((const f32x4*)src)[r_src * 256 + col4];
    bf16x4 h4;
#pragma unroll
    for (int c = 0; c < 4; ++c) h4[c] = (bf16_t)(v[c] * scale);
    ((bf16x4*)(wh + (size_t)z * DMODEL * DMODEL))[i] = h4;
}

// ---------------------------------------------------------------------------
// QKV GEMM C = A * B^T, single-product bf16, 16x16x32 MFMA.
// 128x128x32 tile, 4 waves, double-buffered, 1 barrier/it.
// 1D grid 768, XCD swizzle. z==2 epilogue writes V^T [bh][d][n] directly.
// ---------------------------------------------------------------------------
__global__ __launch_bounds__(256)
void gemm_qkv_kernel(const bf16_t* __restrict__ Ah, const bf16_t* __restrict__ Bh0,
                     bf16_t* __restrict__ Coh0, bf16_t* __restrict__ Vt,
                     int M, int Nn, int Kk) {
    __shared__ __align__(16) bf16_t smem[2][8192];  // 32 KB: A[128x32] | B[128x32]

    const int id = blockIdx.x;
    const int xcd = id & 7;
    const int t = id >> 3;          // 0..95
    const int n0i = t & 7;
    const int u = t >> 3;           // 0..11
    const int z = u >> 2;
    const int m0g = u & 3;
    const int m0 = (m0g * 8 + xcd) * 128;
    const int n0 = n0i * 128;

    const bf16_t* Bh = Bh0 + (size_t)z * Nn * Kk;
    const int tid = threadIdx.x;
    const int wave = tid >> 6, lane = tid & 63, lq = lane >> 4, ln = lane & 15;
    const int wr = wave >> 1, wc = wave & 1;

    // staging: 16 issues (A:8, B:8), 4 per wave
    const bf16_t* g_ptr[4];
    int l_off[4];
#pragma unroll
    for (int q = 0; q < 4; ++q) {
        int e = wave * 4 + q;
        int a = e >> 3, uu = e & 7;
        int C = uu * 64 + lane;
        int r = C >> 2, p = C & 3;
        int c = p ^ ((r >> 1) & 3);           // inverse swizzle on global side
        g_ptr[q] = (a == 0 ? Ah + (size_t)(m0 + r) * Kk
                           : Bh + (size_t)(n0 + r) * Kk) + c * 8;
        l_off[q] = a * 4096 + uu * 512;
    }

    f32x4 acc[4][4] = {};

#pragma unroll
    for (int q = 0; q < 4; ++q)
        async16(g_ptr[q], &smem[0][l_off[q]]);

    const int NIT = Kk / 32;
    for (int j = 0; j < NIT; ++j) {
        __syncthreads();
        if (j + 1 < NIT) {
#pragma unroll
            for (int q = 0; q < 4; ++q)
                async16(g_ptr[q] + (j + 1) * 32, &smem[(j + 1) & 1][l_off[q]]);
        }
        const bf16_t* cur = smem[j & 1];

        bf16x8 ah[4], bh[4];
#pragma unroll
        for (int tt = 0; tt < 4; ++tt) {
            ah[tt] = ldsA32(cur, wr * 64 + tt * 16 + ln, lq);
            bh[tt] = ldsA32(cur + 4096, wc * 64 + tt * 16 + ln, lq);
        }
#pragma unroll
        for (int tm = 0; tm < 4; ++tm)
#pragma unroll
            for (int tn = 0; tn < 4; ++tn)
                acc[tm][tn] = MFMA16(ah[tm], bh[tn], acc[tm][tn]);
    }

    // epilogue. 16x16 C/D: col = lane&15, row = (lane>>4)*4 + reg
    if (z != 2) {
#pragma unroll
        for (int tm = 0; tm < 4; ++tm)
#pragma unroll
            for (int tn = 0; tn < 4; ++tn)
#pragma unroll
                for (int p = 0; p < 4; ++p) {
                    int gm = m0 + wr * 64 + tm * 16 + lq * 4 + p;
                    int gn = n0 + wc * 64 + tn * 16 + ln;
                    Coh0[(size_t)z * M * Nn + (size_t)gm * Nn + gn] =
                        (bf16_t)acc[tm][tn][p];
                }
    } else {
        // V^T: [bh][d][SEQ]; gm -> (b, n), gn -> (h, d); 4 consecutive n per frag
#pragma unroll
        for (int tm = 0; tm < 4; ++tm)
#pragma unroll
            for (int tn = 0; tn < 4; ++tn) {
                int gn = n0 + wc * 64 + tn * 16 + ln;
                int hh = gn >> 6, dd = gn & 63;
                int gm0 = m0 + wr * 64 + tm * 16 + lq * 4;
                int bb = gm0 >> 11, nn = gm0 & 2047;
                bf16x4 v4;
#pragma unroll
                for (int p = 0; p < 4; ++p) v4[p] = (bf16_t)acc[tm][tn][p];
                *(bf16x4*)&Vt[(((size_t)(bb * NHEAD + hh)) * HDIM + dd) * SEQ + nn] = v4;
            }
    }
}

// ---------------------------------------------------------------------------
// Out-proj GEMM: C = A * B^T, single-product bf16, 16x16x32 MFMA, fp32 out.
// 64x128x32 tile, 1D grid 512, XCD swizzle. Double-buffered, 1 barrier/iter.
// ---------------------------------------------------------------------------
__global__ __launch_bounds__(256)
void gemm_out_kernel(const bf16_t* __restrict__ Ah, const bf16_t* __restrict__ Bh,
                     float* __restrict__ Cf, int M, int Nn, int Kk) {
    __shared__ __align__(16) bf16_t smem[2][6144];  // 24 KB: A 64x32 | B 128x32

    const int id = blockIdx.x;
    const int xcd = id & 7;
    const int t = id >> 3;          // 0..63
    const int n0i = t & 7;
    const int m0g = t >> 3;         // 0..7
    const int m0 = (m0g * 8 + xcd) * 64;
    const int n0 = n0i * 128;

    const int tid = threadIdx.x;
    const int wave = tid >> 6, lane = tid & 63, lq = lane >> 4, ln = lane & 15;
    const int wr = wave >> 1, wc = wave & 1;

    // 12 issues (A:4, B:8), 3 per wave
    const bf16_t* g_ptr[3];
    int l_off[3];
#pragma unroll
    for (int q = 0; q < 3; ++q) {
        int e = wave * 3 + q;
        const bf16_t* arr;
        int u, rowbase, lb;
        if (e < 4) { arr = Ah; u = e;     rowbase = m0; lb = 0; }
        else       { arr = Bh; u = e - 4; rowbase = n0; lb = 2048; }
        int r = u * 16 + (lane >> 2), p = lane & 3;
        int c = p ^ ((r >> 1) & 3);
        g_ptr[q] = arr + (size_t)(rowbase + r) * Kk + c * 8;
        l_off[q] = lb + u * 512;
    }

    f32x4 acc[2][4] = {};

#pragma unroll
    for (int q = 0; q < 3; ++q)
        async16(g_ptr[q], &smem[0][l_off[q]]);

    const int NIT = Kk / 32;
    for (int j = 0; j < NIT; ++j) {
        __syncthreads();
        if (j + 1 < NIT) {
#pragma unroll
            for (int q = 0; q < 3; ++q)
                async16(g_ptr[q] + (j + 1) * 32, &smem[(j + 1) & 1][l_off[q]]);
        }
        const bf16_t* cur = smem[j & 1];

        bf16x8 ah[2], bh[4];
#pragma unroll
        for (int tt = 0; tt < 2; ++tt)
            ah[tt] = ldsA32(cur, wr * 32 + tt * 16 + ln, lq);
#pragma unroll
        for (int tt = 0; tt < 4; ++tt)
            bh[tt] = ldsA32(cur + 2048, wc * 64 + tt * 16 + ln, lq);
#pragma unroll
        for (int tm = 0; tm < 2; ++tm)
#pragma unroll
            for (int tn = 0; tn < 4; ++tn)
                acc[tm][tn] = MFMA16(ah[tm], bh[tn], acc[tm][tn]);
    }

#pragma unroll
    for (int tm = 0; tm < 2; ++tm)
#pragma unroll
        for (int tn = 0; tn < 4; ++tn)
#pragma unroll
            for (int p = 0; p < 4; ++p) {
                int gm = m0 + wr * 32 + tm * 16 + lq * 4 + p;
                int gn = n0 + wc * 64 + tn * 16 + ln;
                Cf[(size_t)gm * Nn + gn] = acc[tm][tn][p];
            }
}

// ---------------------------------------------------------------------------
// Flash attention v8: 256 threads = 2 k-groups x 2 waves; each wave owns
// 64 q-rows as TWO 32-q B-strips, so every K/V LDS fragment read feeds two
// MFMA chains (halves fragment traffic vs 4-wave groups; adds in-wave ILP).
// Group g owns keys [g*1024, +1024), double-buffered 64-key K/V tiles.
// XCD-swizzled grid 512. Per-q arithmetic order identical to v7.
// ---------------------------------------------------------------------------
__global__ __launch_bounds__(256, 2)
void attn_kernel(const bf16_t* __restrict__ Qh, const bf16_t* __restrict__ Kh,
                 const bf16_t* __restrict__ Vt, bf16_t* __restrict__ Ch) {
    __shared__ __align__(16) bf16_t smem[2][2][8192];  // [group][buf][K 4096|V 4096]

    const int id = blockIdx.x;
    const int bh = ((id >> 7) << 3) | (id & 7);
    const int qt = (id >> 3) & 15;
    const int b = bh >> 4, h = bh & 15;
    const int q0 = qt * 128;
    const int tid = threadIdx.x;
    const int wave = tid >> 6;                 // 0..3
    const int g = wave >> 1;                   // k-group 0/1
    const int wg = wave & 1;                   // wave in group
    const int lane = tid & 63;
    const int ln32 = lane & 31, hl = lane >> 5;

    // Q fragments for 2 strips: B[q=ln32][k=hl*8+j], chained over hd
    bf16x8 qfh[2][4];
#pragma unroll
    for (int s = 0; s < 2; ++s) {
        size_t qrow = ((size_t)(b * SEQ + q0 + wg * 64 + s * 32 + ln32)) * DMODEL +
                      h * HDIM + hl * 8;
#pragma unroll
        for (int c = 0; c < 4; ++c)
            qfh[s][c] = *(const bf16x8*)&Qh[qrow + c * 16];
    }

    // hoisted fragment-address terms (rows kt*32+ln32: row&7 == ln32&7)
    const int xrow = ln32 * 64;
    int xc[4];
#pragma unroll
    for (int c = 0; c < 4; ++c)
        xc[c] = (((2 * c + hl) ^ (ln32 & 7)) << 3) + xrow;

    // staging: per group 16 issues (K:8 by wg=0, V:8 by wg=1)
    bf16_t* gsm = &smem[g][0][0];
    const bf16_t* g_cur[8];
    int l_off[8];
    size_t g_step[8];
#pragma unroll
    for (int q = 0; q < 8; ++q) {
        int e = wg * 8 + q;                    // 0..15
        int a = e >> 3, u = e & 7;
        int r = u * 8 + (lane >> 3), p = lane & 7;
        int c = p ^ (r & 7);                   // inverse swizzle on global side
        if (a == 0) {                          // K tile [64 keys][64 el]
            g_cur[q] = Kh + ((size_t)(b * SEQ + g * 1024 + r)) * DMODEL +
                       h * HDIM + c * 8;
            l_off[q] = u * 512;
            g_step[q] = (size_t)64 * DMODEL;
        } else {                               // V^T tile [64 d][64 keys]
            g_cur[q] = Vt + ((size_t)(bh * HDIM + r)) * SEQ + g * 1024 + c * 8;
            l_off[q] = 4096 + u * 512;
            g_step[q] = 64;
        }
    }

    f32x16 o[2][2];                            // [strip][dt]
#pragma unroll
    for (int s = 0; s < 2; ++s)
#pragma unroll
        for (int dt = 0; dt < 2; ++dt)
#pragma unroll
            for (int r = 0; r < 16; ++r) o[s][dt][r] = 0.0f;
    float rs[2] = {0.0f, 0.0f};

#pragma unroll
    for (int q = 0; q < 8; ++q) {
        async16(g_cur[q], gsm + l_off[q]);
        g_cur[q] += g_step[q];
    }

    for (int j = 0; j < 16; ++j) {
        __syncthreads();  // buf j&1 DMA landed; reads of buf (j+1)&1 done
        if (j < 15) {
#pragma unroll
            for (int q = 0; q < 8; ++q) {
                async16(g_cur[q], gsm + ((j + 1) & 1) * 8192 + l_off[q]);
                g_cur[q] += g_step[q];
            }
        }
        const bf16_t* Kc = gsm + (j & 1) * 8192;
        const bf16_t* Vc = Kc + 4096;

        bf16x8 pfrag[2][4];                    // [strip][key subgroup]
#pragma unroll
        for (int kt = 0; kt < 2; ++kt) {
            // S^T subtiles for both strips, K fragments read once
            f32x16 st0, st1;
#pragma unroll
            for (int r = 0; r < 16; ++r) { st0[r] = 0.0f; st1[r] = 0.0f; }
#pragma unroll
            for (int c = 0; c < 4; ++c) {
                bf16x8 kh = *(const bf16x8*)&Kc[kt * 2048 + xc[c]];
                st0 = MFMA32(kh, qfh[0][c], st0);
                st1 = MFMA32(kh, qfh[1][c], st1);
            }
#pragma unroll
            for (int s = 0; s < 2; ++s) {
                float pexp[16];
#pragma unroll
                for (int r = 0; r < 16; ++r) {
                    pexp[r] = __builtin_amdgcn_exp2f(s == 0 ? st0[r] : st1[r]);
                    rs[s] += pexp[r];
                }
#pragma unroll
                for (int s1 = 0; s1 < 2; ++s1) {
                    unsigned lo01 = pk(pexp[8 * s1 + 0], pexp[8 * s1 + 1]);
                    unsigned lo23 = pk(pexp[8 * s1 + 2], pexp[8 * s1 + 3]);
                    unsigned hi01 = pk(pexp[8 * s1 + 4], pexp[8 * s1 + 5]);
                    unsigned hi23 = pk(pexp[8 * s1 + 6], pexp[8 * s1 + 7]);
                    unsigned sa = hl ? lo01 : hi01;
                    unsigned sb = hl ? lo23 : hi23;
                    unsigned ra = (unsigned)__shfl_xor((int)sa, 32);
                    unsigned rb = (unsigned)__shfl_xor((int)sb, 32);
                    union { bf16x8 v; unsigned u[4]; } outv;
                    outv.u[0] = hl ? ra : lo01;
                    outv.u[1] = hl ? rb : lo23;
                    outv.u[2] = hl ? hi01 : ra;
                    outv.u[3] = hl ? hi23 : rb;
                    pfrag[s][kt * 2 + s1] = outv.v;
                }
            }
        }
        // O^T += V^T * P: V fragments read once, feed both strips
#pragma unroll
        for (int sg = 0; sg < 4; ++sg) {
            bf16x8 va0 = *(const bf16x8*)&Vc[xc[sg]];
            bf16x8 va1 = *(const bf16x8*)&Vc[2048 + xc[sg]];
            o[0][0] = MFMA32(va0, pfrag[0][sg], o[0][0]);
            o[1][0] = MFMA32(va0, pfrag[1][sg], o[1][0]);
            o[0][1] = MFMA32(va1, pfrag[0][sg], o[0][1]);
            o[1][1] = MFMA32(va1, pfrag[1][sg], o[1][1]);
        }
    }

    rs[0] += __shfl_xor(rs[0], 32);
    rs[1] += __shfl_xor(rs[1], 32);

    // ---- combine the two groups' partials (additive) ----
    __syncthreads();                                 // (A) j-loop reads done
    float* cbuf = (float*)smem;                      // 64 d x 128 q f32
    float* rbuf = cbuf + 8192;                       // 128 row sums
    if (g == 1) {
#pragma unroll
        for (int s = 0; s < 2; ++s) {
            int qcol = wg * 64 + s * 32 + ln32;
#pragma unroll
            for (int dt = 0; dt < 2; ++dt)
#pragma unroll
                for (int r = 0; r < 16; ++r) {
                    int d = dt * 32 + (r & 3) + 8 * (r >> 2) + 4 * hl;
                    cbuf[d * 128 + qcol] = o[s][dt][r];
                }
            if (hl == 0) rbuf[qcol] = rs[s];
        }
    }
    __syncthreads();                                 // (B)
    float inv[2] = {0.0f, 0.0f};
    if (g == 0) {
#pragma unroll
        for (int s = 0; s < 2; ++s) {
            int qcol = wg * 64 + s * 32 + ln32;
#pragma unroll
            for (int dt = 0; dt < 2; ++dt)
#pragma unroll
                for (int r = 0; r < 16; ++r) {
                    int d = dt * 32 + (r & 3) + 8 * (r >> 2) + 4 * hl;
                    o[s][dt][r] += cbuf[d * 128 + qcol];
                }
            inv[s] = 1.0f / (rs[s] + rbuf[qcol]);
        }
    }
    __syncthreads();                                 // (C) combine reads done
    float* fbuf = (float*)smem;                      // [dh][strip v][32q][33]
    if (g == 0) {
#pragma unroll
        for (int s = 0; s < 2; ++s) {
            int v = wg * 2 + s;                      // strip region 0..3
#pragma unroll
            for (int dh = 0; dh < 2; ++dh)
#pragma unroll
                for (int r = 0; r < 16; ++r) {
                    int d_loc = (r & 3) + 8 * (r >> 2) + 4 * hl;
                    fbuf[dh * 4224 + v * 1056 + ln32 * 33 + d_loc] =
                        o[s][dh][r] * inv[s];
                }
        }
    }
    __syncthreads();                                 // (D)
    // 4 waves write: wave w covers strip v=w, both dh halves
    {
        int v = wave;
#pragma unroll
        for (int dh = 0; dh < 2; ++dh)
#pragma unroll
            for (int qq = 0; qq < 16; ++qq) {
                int qrow = hl * 16 + qq;
                float val = fbuf[dh * 4224 + v * 1056 + qrow * 33 + ln32];
                size_t gidx = ((size_t)(b * SEQ + q0 + v * 32 + qrow)) * DMODEL +
                              h * HDIM + dh * 32 + ln32;
                Ch[gidx] = (bf16_t)val;
            }
    }
}

// ---------------------------------------------------------------------------
extern "C" void kernel_launch(void* const* d_in, const int* in_sizes, int n_in,
                              void* d_out, int out_size, void* d_ws, size_t ws_size,
                              hipStream_t stream) {
    const float* x  = (const float*)d_in[0];
    const float* Wq = (const float*)d_in[1];
    const float* Wk = (const float*)d_in[2];
    const float* Wv = (const float*)d_in[3];
    const float* Wo = (const float*)d_in[4];
    float* out = (float*)d_out;

    char* ws = (char*)d_ws;
    size_t off = 0;
    auto alloc = [&](size_t bytes) -> bf16_t* {
        bf16_t* p = (bf16_t*)(ws + off);
        off += (bytes + 255) & ~(size_t)255;
        return p;
    };
    const size_t XE = (size_t)MROWS * DMODEL;      // 4,194,304
    const size_t WE = (size_t)DMODEL * DMODEL;     // 1,048,576

    bf16_t* xh  = alloc(XE * 2);
    bf16_t* wh  = alloc(4 * WE * 2);   // q,k,v,o (q/k/v row-reordered, q scaled)
    bf16_t* qnh = alloc(3 * XE * 2);   // Q,K in concat layout (z==2 slab unused)
    bf16_t* vth = alloc(XE * 2);       // V^T per head (written by QKV epilogue)
    bf16_t* ch  = alloc(XE * 2);       // attn output
    (void)ws_size; (void)in_sizes; (void)n_in; (void)out_size;

    // 1. fused splits (hi only)
    split_kernel<<<8192, 256, 0, stream>>>(x, Wq, Wk, Wv, Wo, xh, wh);

    // 2. QKV projections (MFMA16) + fused V-transpose epilogue
    gemm_qkv_kernel<<<768, 256, 0, stream>>>(xh, wh, qnh, vth, MROWS, DMODEL, DMODEL);

    // 3. flash attention (split-K groups, 64q waves), XCD-swizzled
    attn_kernel<<<512, 256, 0, stream>>>(qnh, qnh + XE, vth, ch);

    // 4. output projection (MFMA16, single-product) -> fp32 d_out
    gemm_out_kernel<<<512, 256, 0, stream>>>(ch, wh + 3 * WE, out, MROWS, DMODEL, DMODEL);
}